// Round 20
// baseline (68.784 us; speedup 1.0000x reference)
//
#include <hip/hip_runtime.h>
#include <hip/hip_bf16.h>
#include <stdint.h>

#define T_TOK 8192
#define D_IN  512
#define DINT  256
#define NE    8

typedef float f32x4 __attribute__((ext_vector_type(4)));
typedef short bf16x8 __attribute__((ext_vector_type(8)));
typedef unsigned short u16;
typedef unsigned short u16x4 __attribute__((ext_vector_type(4)));

// ws layout (bytes) — identical to R19
#define WS_CNT   0                 // int[8]
#define WS_WP    1024              // f32[16384]           -> 66560
#define WS_BT    66560             // u16[8][8192]         -> 197632
#define WS_F2B   197632            // bf16 fc2 staged (2MB)-> 2294784
#define WS_F1B   2294784           // bf16 fc1 staged (4MB)-> 6489088
#define WS_XB    6489088           // bf16 xb [8192][512]  -> 14877696
#define WS_AS    14877696          // bf16 act staged, 135 tiles x 64KB -> 23725056
#define WS_OG    23725056          // bf16 og [16384][512] -> 40502272

typedef const __attribute__((address_space(1))) void* gptr_t;
typedef __attribute__((address_space(3))) void* lptr_t;
#define GLL16(g, s) __builtin_amdgcn_global_load_lds((gptr_t)(g), (lptr_t)(s), 16, 0, 0)

static __device__ __forceinline__ u16 f32_bf16(float f) {
    union { float f; uint32_t u; } v; v.f = f;
    uint32_t u = v.u;
    uint32_t r = (u + 0x7FFFu + ((u >> 16) & 1u)) >> 16;   // RTNE
    return (u16)r;
}
static __device__ __forceinline__ float bf16_f32(u16 h) {
    union { uint32_t u; float f; } v; v.u = ((uint32_t)h) << 16; return v.f;
}

// -- 0. prep: zero cnt (must precede gate's atomics) ------------------------
__global__ __launch_bounds__(64) void prep_kernel(int* __restrict__ cnt)
{
    if (threadIdx.x < NE) cnt[threadIdx.x] = 0;
}

// -- 1. gate + weight staging: 256 blocks x 32 tokens, then 4 cvt panels ----
__global__ __launch_bounds__(256) void gate_kernel(
    const float* __restrict__ x, const float* __restrict__ wg,
    int* __restrict__ cnt, u16* __restrict__ bt, float* __restrict__ wpair,
    u16* __restrict__ xb,
    const float* __restrict__ fc1, const float* __restrict__ fc2,
    u16* __restrict__ f1s, u16* __restrict__ f2s)
{
    __shared__ float wgl[NE * D_IN];
    __shared__ float xt[256][33];        // cvt panel tile overlays this
    __shared__ float part[256 * 9];
    __shared__ int ecnt[NE];
    __shared__ int gbase[NE];

    const int tid = threadIdx.x;
    const int t0  = blockIdx.x * 32;
    const int tl  = tid & 31;
    const int kq  = tid >> 5;

    for (int i = tid; i < NE * D_IN; i += 256) wgl[i] = wg[i];
    if (tid < NE) ecnt[tid] = 0;

    float acc[NE];
#pragma unroll
    for (int e = 0; e < NE; e++) acc[e] = 0.f;

    for (int c = 0; c < 2; ++c) {
        __syncthreads();
#pragma unroll
        for (int i = 0; i < 8; ++i) {
            int idx = i * 256 + tid;
            int row = idx >> 6, c4 = idx & 63;
            float4 v = *(const float4*)&x[(size_t)(t0 + row) * D_IN + c * 256 + c4 * 4];
            u16x4 o;
            o.x = f32_bf16(v.x); o.y = f32_bf16(v.y);
            o.z = f32_bf16(v.z); o.w = f32_bf16(v.w);
            *(u16x4*)&xb[(size_t)(t0 + row) * D_IN + c * 256 + c4 * 4] = o;
            xt[c4 * 4 + 0][row] = v.x; xt[c4 * 4 + 1][row] = v.y;
            xt[c4 * 4 + 2][row] = v.z; xt[c4 * 4 + 3][row] = v.w;
        }
        __syncthreads();
#pragma unroll
        for (int j = 0; j < 32; ++j) {
            float xv = xt[kq * 32 + j][tl];
#pragma unroll
            for (int e = 0; e < NE; e++)
                acc[e] = fmaf(xv, wgl[e * D_IN + c * 256 + kq * 32 + j], acc[e]);
        }
    }
#pragma unroll
    for (int e = 0; e < NE; e++) part[tid * 9 + e] = acc[e];
    __syncthreads();

    int i1 = 0, i2 = -1, lp1 = 0, lp2 = 0;
    if (tid < 32) {
        float s8[NE];
#pragma unroll
        for (int e = 0; e < NE; e++) {
            float s = 0.f;
#pragma unroll
            for (int q = 0; q < 8; q++) s += part[(q * 32 + tid) * 9 + e];
            s8[e] = s;
        }
        float m = s8[0];
#pragma unroll
        for (int e = 1; e < NE; e++) m = fmaxf(m, s8[e]);
        float p[NE], s = 0.f;
#pragma unroll
        for (int e = 0; e < NE; e++) { p[e] = expf(s8[e] - m); s += p[e]; }
        float inv = 1.f / s;
        float v1 = p[0];
#pragma unroll
        for (int e = 1; e < NE; e++) if (p[e] > v1) { v1 = p[e]; i1 = e; }
        float v2 = -1.f;
#pragma unroll
        for (int e = 0; e < NE; e++) if (e != i1 && p[e] > v2) { v2 = p[e]; i2 = e; }
        int t = t0 + tid;
        wpair[2 * t]     = v1 * inv;
        wpair[2 * t + 1] = v2 * inv;
        lp1 = atomicAdd(&ecnt[i1], 1);
        lp2 = atomicAdd(&ecnt[i2], 1);
    }
    __syncthreads();
    if (tid < NE) gbase[tid] = atomicAdd(&cnt[tid], ecnt[tid]);
    __syncthreads();
    if (tid < 32) {
        int t = t0 + tid;
        bt[i1 * T_TOK + gbase[i1] + lp1] = (u16)(2 * t);
        bt[i2 * T_TOK + gbase[i2] + lp2] = (u16)(2 * t + 1);
    }

    // ---- appended weight staging: 4 panels per block (R19 cvt, verbatim) ----
    u16* lds2 = (u16*)&xt[0][0];         // 16.9KB needed < 33.8KB (xt dead now)
    __syncthreads();
#pragma unroll
    for (int pi = 0; pi < 4; ++pi) {
        const int b = blockIdx.x * 4 + pi;          // 0..1023
        if (b < 512) {
            const int bb = b >> 1, kh = b & 1;
            const int e_ = bb >> 5, nt_ = (bb >> 3) & 3, f_ = bb & 7;
            const int base_row = (f_ < 4) ? (nt_ * 64 + f_ * 16)
                                          : (256 + nt_ * 64 + (f_ - 4) * 16);
            const float* src = fc1 + (size_t)e_ * 512 * 512 + (size_t)base_row * 512 + kh * 256;
#pragma unroll
            for (int it = 0; it < 4; ++it) {
                int idx = it * 256 + tid;
                int r = idx >> 6, c4 = idx & 63;
                float4 v = *(const float4*)&src[(size_t)r * 512 + c4 * 4];
                u16x4 o;
                o.x = f32_bf16(v.x); o.y = f32_bf16(v.y);
                o.z = f32_bf16(v.z); o.w = f32_bf16(v.w);
                *(u16x4*)&lds2[r * 264 + c4 * 4] = o;
            }
            __syncthreads();
            u16* dst = f1s + (size_t)(e_ * 4 + nt_) * 65536 + f_ * 512;
#pragma unroll
            for (int it = 0; it < 2; ++it) {
                int c = it * 256 + tid;
                int ksl = c >> 6, lane = c & 63;
                int l15 = lane & 15, lhi = lane >> 4;
                bf16x8 v = *(const bf16x8*)&lds2[l15 * 264 + ksl * 32 + lhi * 8];
                *(bf16x8*)&dst[(size_t)(kh * 8 + ksl) * 4096 + lane * 8] = v;
            }
            __syncthreads();
        } else {
            const int bb = (b - 512) >> 1, kh = b & 1;
            const int e_ = bb >> 5, nt_ = (bb >> 3) & 3, f_ = bb & 7;
            const int base_row = nt_ * 128 + f_ * 16;
            const float* src = fc2 + (size_t)e_ * 512 * 256 + (size_t)base_row * 256 + kh * 128;
#pragma unroll
            for (int it = 0; it < 2; ++it) {
                int idx = it * 256 + tid;
                int r = idx >> 5, c4 = idx & 31;
                float4 v = *(const float4*)&src[(size_t)r * 256 + c4 * 4];
                u16x4 o;
                o.x = f32_bf16(v.x); o.y = f32_bf16(v.y);
                o.z = f32_bf16(v.z); o.w = f32_bf16(v.w);
                *(u16x4*)&lds2[r * 264 + c4 * 4] = o;
            }
            __syncthreads();
            u16* dst = f2s + (size_t)(e_ * 4 + nt_) * 32768 + f_ * 512;
            {
                int c = tid;
                int ksl = c >> 6, lane = c & 63;
                int l15 = lane & 15, lhi = lane >> 4;
                bf16x8 v = *(const bf16x8*)&lds2[l15 * 264 + ksl * 32 + lhi * 8];
                *(bf16x8*)&dst[(size_t)(kh * 4 + ksl) * 4096 + lane * 8] = v;
            }
            __syncthreads();
        }
    }
}

// -- 2. fc1 + GLU -> act_s: 64-row M-tiles, 2-phase loop (identical to R19) --
__global__ __launch_bounds__(256) void fc1_kernel(
    const u16* __restrict__ xb, const u16* __restrict__ f1s,
    const int* __restrict__ cnt, const u16* __restrict__ bt,
    u16* __restrict__ acts)
{
    __shared__ __align__(16) u16 asl[2][2048];
    __shared__ __align__(16) u16 bsl[2][4096];
    __shared__ u16 slot_l[64];

    const int bid = blockIdx.x;
    const int e   = bid & 7;
    const int nt  = (bid >> 3) & 3;
    const int mt  = bid >> 5;
    const int n   = cnt[e];
    const int row0 = mt * 64;
    if (row0 >= n) return;

    int tpre = 0;
#pragma unroll
    for (int ee = 0; ee < NE; ++ee)
        if (ee < e) tpre += (cnt[ee] + 127) >> 7;
    const int g = tpre + (mt >> 1);
    const int mhalf = mt & 1;

    const int tid = threadIdx.x;
    const int wv  = tid >> 6, lane = tid & 63;
    const int l15 = lane & 15, lhi = lane >> 4;
    const int wr  = wv >> 1, wc = wv & 1;

    if (tid < 64) {
        int r = row0 + tid;
        slot_l[tid] = bt[e * T_TOK + ((r < n) ? r : (n - 1))];
    }
    __syncthreads();

    const u16* srcA  = xb + (size_t)(slot_l[wv * 16 + l15] >> 1) * D_IN + lhi * 8;
    const int fb0 = wv * 2, fb1 = wv * 2 + 1;
    const u16* srcB0 = f1s + (size_t)(e * 4 + nt) * 65536 + fb0 * 512 + lane * 8;
    const u16* srcB1 = f1s + (size_t)(e * 4 + nt) * 65536 + fb1 * 512 + lane * 8;

#define ISS1(KS, BUF) {                                          \
    GLL16(srcA  + (KS) * 32,   &asl[BUF][wv * 512]);             \
    GLL16(srcB0 + (KS) * 4096, &bsl[BUF][fb0 * 512]);            \
    GLL16(srcB1 + (KS) * 4096, &bsl[BUF][fb1 * 512]); }

    f32x4 acc[2][4];
#pragma unroll
    for (int m = 0; m < 2; m++)
#pragma unroll
        for (int nb = 0; nb < 4; nb++) acc[m][nb] = (f32x4)0.f;

    ISS1(0, 0);
    __syncthreads();

#pragma unroll
    for (int ks = 0; ks < 16; ++ks) {
        const int cur = ks & 1;
        if (ks < 15) ISS1(ks + 1, cur ^ 1);
        bf16x8 a[2], b[4];
#pragma unroll
        for (int m = 0; m < 2; m++)
            a[m] = *(const bf16x8*)&asl[cur][(wr * 2 + m) * 512 + lane * 8];
        b[0] = *(const bf16x8*)&bsl[cur][(wc * 2 + 0) * 512 + lane * 8];
        b[1] = *(const bf16x8*)&bsl[cur][(wc * 2 + 1) * 512 + lane * 8];
        b[2] = *(const bf16x8*)&bsl[cur][(4 + wc * 2 + 0) * 512 + lane * 8];
        b[3] = *(const bf16x8*)&bsl[cur][(4 + wc * 2 + 1) * 512 + lane * 8];
#pragma unroll
        for (int m = 0; m < 2; m++)
#pragma unroll
            for (int nb = 0; nb < 4; nb++)
                acc[m][nb] = __builtin_amdgcn_mfma_f32_16x16x32_bf16(
                    a[m], b[nb], acc[m][nb], 0, 0, 0);
        __syncthreads();
    }

    u16* glu = &bsl[0][0];
#pragma unroll
    for (int m = 0; m < 2; m++) {
#pragma unroll
        for (int j = 0; j < 4; j++) {
            int row = wr * 32 + m * 16 + lhi * 4 + j;
#pragma unroll
            for (int q = 0; q < 2; q++) {
                float y = acc[m][q][j], gv = acc[m][q + 2][j];
                float v = y * gv / (1.f + __expf(-gv));
                glu[row * 72 + wc * 32 + q * 16 + l15] = f32_bf16(v);
            }
        }
    }
    __syncthreads();

    u16* tile = acts + (size_t)g * 32768;
#pragma unroll
    for (int i = 0; i < 2; ++i) {
        int c = wv * 2 + i;
        int mfl = c >> 1, ksr = c & 1;
        bf16x8 v = *(const bf16x8*)&glu[(mfl * 16 + l15) * 72 + ksr * 32 + lhi * 8];
        *(bf16x8*)&tile[(2 * nt + ksr) * 4096 + (mhalf * 4 + mfl) * 512 + lane * 8] = v;
    }
#undef ISS1
}

// -- 3. fc2 -> og: 64-row M-tiles, 2-phase loop (identical to R19) -----------
__global__ __launch_bounds__(256) void fc2_kernel(
    const u16* __restrict__ acts, const u16* __restrict__ f2s,
    const int* __restrict__ cnt, const u16* __restrict__ bt,
    u16* __restrict__ og)
{
    __shared__ __align__(16) u16 asl[2][2048];
    __shared__ __align__(16) u16 bsl[2][4096];
    __shared__ u16 slot_l[64];

    const int bid = blockIdx.x;
    const int e   = bid & 7;
    const int nt  = (bid >> 3) & 3;
    const int mt  = bid >> 5;
    const int n   = cnt[e];
    const int row0 = mt * 64;
    if (row0 >= n) return;

    int tpre = 0;
#pragma unroll
    for (int ee = 0; ee < NE; ++ee)
        if (ee < e) tpre += (cnt[ee] + 127) >> 7;
    const int g = tpre + (mt >> 1);
    const int mhalf = mt & 1;

    const int tid = threadIdx.x;
    const int wv  = tid >> 6, lane = tid & 63;
    const int l15 = lane & 15, lhi = lane >> 4;
    const int wr  = wv >> 1, wc = wv & 1;

    if (tid < 64) {
        int r = row0 + tid;
        slot_l[tid] = bt[e * T_TOK + ((r < n) ? r : (n - 1))];
    }
    __syncthreads();

    const int fb0 = wv * 2, fb1 = wv * 2 + 1;
    const u16* srcA  = acts + (size_t)g * 32768 + (mhalf * 4 + wv) * 512 + lane * 8;
    const u16* srcB0 = f2s + (size_t)(e * 4 + nt) * 32768 + fb0 * 512 + lane * 8;
    const u16* srcB1 = f2s + (size_t)(e * 4 + nt) * 32768 + fb1 * 512 + lane * 8;

#define ISS2(KS, BUF) {                                          \
    GLL16(srcA  + (KS) * 4096, &asl[BUF][wv * 512]);             \
    GLL16(srcB0 + (KS) * 4096, &bsl[BUF][fb0 * 512]);            \
    GLL16(srcB1 + (KS) * 4096, &bsl[BUF][fb1 * 512]); }

    f32x4 acc[2][4];
#pragma unroll
    for (int m = 0; m < 2; m++)
#pragma unroll
        for (int nb = 0; nb < 4; nb++) acc[m][nb] = (f32x4)0.f;

    ISS2(0, 0);
    __syncthreads();

#pragma unroll
    for (int ks = 0; ks < 8; ++ks) {
        const int cur = ks & 1;
        if (ks < 7) ISS2(ks + 1, cur ^ 1);
        bf16x8 a[2], b[4];
#pragma unroll
        for (int m = 0; m < 2; m++)
            a[m] = *(const bf16x8*)&asl[cur][(wr * 2 + m) * 512 + lane * 8];
#pragma unroll
        for (int nb = 0; nb < 4; nb++)
            b[nb] = *(const bf16x8*)&bsl[cur][(wc * 4 + nb) * 512 + lane * 8];
#pragma unroll
        for (int m = 0; m < 2; m++)
#pragma unroll
            for (int nb = 0; nb < 4; nb++)
                acc[m][nb] = __builtin_amdgcn_mfma_f32_16x16x32_bf16(
                    a[m], b[nb], acc[m][nb], 0, 0, 0);
        __syncthreads();
    }

#pragma unroll
    for (int m = 0; m < 2; m++) {
#pragma unroll
        for (int j = 0; j < 4; j++) {
            int lrow = wr * 32 + m * 16 + lhi * 4 + j;
            if (row0 + lrow < n) {
                int slot = slot_l[lrow];
                u16* dst = og + (size_t)slot * D_IN + nt * 128 + wc * 64 + l15;
#pragma unroll
                for (int nb = 0; nb < 4; nb++)
                    dst[nb * 16] = f32_bf16(acc[m][nb][j]);
            }
        }
    }
#undef ISS2
}

// ---------------- 4. combine (identical to R19) ----------------
__global__ __launch_bounds__(256) void combine_kernel(
    const u16* __restrict__ og, const float* __restrict__ wpair,
    float* __restrict__ out)
{
    int idx = blockIdx.x * 256 + threadIdx.x;
    int t  = idx >> 6;
    int c8 = (idx & 63) * 8;
    float w0 = wpair[2 * t], w1 = wpair[2 * t + 1];
    bf16x8 a = *(const bf16x8*)&og[(size_t)(2 * t) * D_IN + c8];
    bf16x8 b = *(const bf16x8*)&og[(size_t)(2 * t + 1) * D_IN + c8];
    float4 o0, o1;
#pragma unroll
    for (int j = 0; j < 4; j++) {
        o0[j] = w0 * bf16_f32((u16)a[j])     + w1 * bf16_f32((u16)b[j]);
        o1[j] = w0 * bf16_f32((u16)a[j + 4]) + w1 * bf16_f32((u16)b[j + 4]);
    }
    float* orow = out + (size_t)t * D_IN + c8;
    *(float4*)orow = o0;
    *(float4*)(orow + 4) = o1;
}

// ---------------- launch ----------------
extern "C" void kernel_launch(void* const* d_in, const int* in_sizes, int n_in,
                              void* d_out, int out_size, void* d_ws, size_t ws_size,
                              hipStream_t stream) {
    const float* x   = (const float*)d_in[0];
    const float* wg  = (const float*)d_in[1];
    const float* fc1 = (const float*)d_in[2];
    const float* fc2 = (const float*)d_in[3];
    float* out = (float*)d_out;
    char* ws = (char*)d_ws;

    int*   cnt   = (int*)(ws + WS_CNT);
    float* wpair = (float*)(ws + WS_WP);
    u16*   bt    = (u16*)(ws + WS_BT);
    u16*   f2s   = (u16*)(ws + WS_F2B);
    u16*   f1s   = (u16*)(ws + WS_F1B);
    u16*   xb    = (u16*)(ws + WS_XB);
    u16*   acts  = (u16*)(ws + WS_AS);
    u16*   og    = (u16*)(ws + WS_OG);

    prep_kernel<<<1, 64, 0, stream>>>(cnt);
    gate_kernel<<<T_TOK / 32, 256, 0, stream>>>(x, wg, cnt, bt, wpair, xb,
                                                fc1, fc2, f1s, f2s);
    fc1_kernel<<<4096, 256, 0, stream>>>(xb, f1s, cnt, bt, acts);
    fc2_kernel<<<4096, 256, 0, stream>>>(acts, f2s, cnt, bt, og);
    combine_kernel<<<T_TOK * (D_IN / 8) / 256, 256, 0, stream>>>(og, wpair, out);
}

// Round 21
// 65.894 us; speedup vs baseline: 1.0439x; 1.0439x over previous
//
#include <hip/hip_runtime.h>
#include <hip/hip_bf16.h>
#include <stdint.h>

#define T_TOK 8192
#define D_IN  512
#define DINT  256
#define NE    8

typedef float f32x4 __attribute__((ext_vector_type(4)));
typedef short bf16x8 __attribute__((ext_vector_type(8)));
typedef unsigned short u16;
typedef unsigned short u16x4 __attribute__((ext_vector_type(4)));

// ws layout (bytes)
#define WS_CNT   0                 // int[8]
#define WS_WP    1024              // f32[16384]           -> 66560
#define WS_BT    66560             // u16[8][8192]         -> 197632
#define WS_F2B   197632            // bf16 fc2 staged (2MB)-> 2294784
#define WS_F1B   2294784           // bf16 fc1 staged (4MB)-> 6489088
#define WS_XB    6489088           // bf16 xb [8192][512]  -> 14877696
#define WS_AS    14877696          // bf16 act staged, 135 tiles x 64KB -> 23725056
#define WS_OG    23725056          // bf16 og [16384][512] -> 40502272

typedef const __attribute__((address_space(1))) void* gptr_t;
typedef __attribute__((address_space(3))) void* lptr_t;
#define GLL16(g, s) __builtin_amdgcn_global_load_lds((gptr_t)(g), (lptr_t)(s), 16, 0, 0)

static __device__ __forceinline__ u16 f32_bf16(float f) {
    union { float f; uint32_t u; } v; v.f = f;
    uint32_t u = v.u;
    uint32_t r = (u + 0x7FFFu + ((u >> 16) & 1u)) >> 16;   // RTNE
    return (u16)r;
}
static __device__ __forceinline__ float bf16_f32(u16 h) {
    union { uint32_t u; float f; } v; v.u = ((uint32_t)h) << 16; return v.f;
}

// -- 1. cvt: coalesced reads -> LDS transpose -> coalesced fragment stores --
__global__ __launch_bounds__(256) void cvt_kernel(
    const float* __restrict__ fc1, const float* __restrict__ fc2,
    u16* __restrict__ f1s, u16* __restrict__ f2s, int* __restrict__ cnt)
{
    __shared__ u16 lds[16 * 264];
    const int b   = blockIdx.x;
    const int tid = threadIdx.x;
    if (b == 0 && tid < NE) cnt[tid] = 0;

    if (b < 512) {
        const int bb = b >> 1, kh = b & 1;
        const int e_ = bb >> 5, nt_ = (bb >> 3) & 3, f_ = bb & 7;
        const int base_row = (f_ < 4) ? (nt_ * 64 + f_ * 16)
                                      : (256 + nt_ * 64 + (f_ - 4) * 16);
        const float* src = fc1 + (size_t)e_ * 512 * 512 + (size_t)base_row * 512 + kh * 256;
#pragma unroll
        for (int it = 0; it < 4; ++it) {
            int idx = it * 256 + tid;
            int r = idx >> 6, c4 = idx & 63;
            float4 v = *(const float4*)&src[(size_t)r * 512 + c4 * 4];
            u16x4 o;
            o.x = f32_bf16(v.x); o.y = f32_bf16(v.y);
            o.z = f32_bf16(v.z); o.w = f32_bf16(v.w);
            *(u16x4*)&lds[r * 264 + c4 * 4] = o;
        }
        __syncthreads();
        u16* dst = f1s + (size_t)(e_ * 4 + nt_) * 65536 + f_ * 512;
#pragma unroll
        for (int it = 0; it < 2; ++it) {
            int c = it * 256 + tid;
            int ksl = c >> 6, lane = c & 63;
            int l15 = lane & 15, lhi = lane >> 4;
            bf16x8 v = *(const bf16x8*)&lds[l15 * 264 + ksl * 32 + lhi * 8];
            *(bf16x8*)&dst[(size_t)(kh * 8 + ksl) * 4096 + lane * 8] = v;
        }
    } else {
        const int bb = (b - 512) >> 1, kh = b & 1;
        const int e_ = bb >> 5, nt_ = (bb >> 3) & 3, f_ = bb & 7;
        const int base_row = nt_ * 128 + f_ * 16;
        const float* src = fc2 + (size_t)e_ * 512 * 256 + (size_t)base_row * 256 + kh * 128;
#pragma unroll
        for (int it = 0; it < 2; ++it) {
            int idx = it * 256 + tid;
            int r = idx >> 5, c4 = idx & 31;
            float4 v = *(const float4*)&src[(size_t)r * 256 + c4 * 4];
            u16x4 o;
            o.x = f32_bf16(v.x); o.y = f32_bf16(v.y);
            o.z = f32_bf16(v.z); o.w = f32_bf16(v.w);
            *(u16x4*)&lds[r * 264 + c4 * 4] = o;
        }
        __syncthreads();
        u16* dst = f2s + (size_t)(e_ * 4 + nt_) * 32768 + f_ * 512;
        {
            int c = tid;
            int ksl = c >> 6, lane = c & 63;
            int l15 = lane & 15, lhi = lane >> 4;
            bf16x8 v = *(const bf16x8*)&lds[l15 * 264 + ksl * 32 + lhi * 8];
            *(bf16x8*)&dst[(size_t)(kh * 4 + ksl) * 4096 + lane * 8] = v;
        }
    }
}

// -- 2. gate: 256 blocks x 32 tokens ----------------------------------------
__global__ __launch_bounds__(256) void gate_kernel(
    const float* __restrict__ x, const float* __restrict__ wg,
    int* __restrict__ cnt, u16* __restrict__ bt, float* __restrict__ wpair,
    u16* __restrict__ xb)
{
    __shared__ float wgl[NE * D_IN];
    __shared__ float xt[256][33];
    __shared__ float part[256 * 9];
    __shared__ int ecnt[NE];
    __shared__ int gbase[NE];

    const int tid = threadIdx.x;
    const int t0  = blockIdx.x * 32;
    const int tl  = tid & 31;
    const int kq  = tid >> 5;

    for (int i = tid; i < NE * D_IN; i += 256) wgl[i] = wg[i];
    if (tid < NE) ecnt[tid] = 0;

    float acc[NE];
#pragma unroll
    for (int e = 0; e < NE; e++) acc[e] = 0.f;

    for (int c = 0; c < 2; ++c) {
        __syncthreads();
#pragma unroll
        for (int i = 0; i < 8; ++i) {
            int idx = i * 256 + tid;
            int row = idx >> 6, c4 = idx & 63;
            float4 v = *(const float4*)&x[(size_t)(t0 + row) * D_IN + c * 256 + c4 * 4];
            u16x4 o;
            o.x = f32_bf16(v.x); o.y = f32_bf16(v.y);
            o.z = f32_bf16(v.z); o.w = f32_bf16(v.w);
            *(u16x4*)&xb[(size_t)(t0 + row) * D_IN + c * 256 + c4 * 4] = o;
            xt[c4 * 4 + 0][row] = v.x; xt[c4 * 4 + 1][row] = v.y;
            xt[c4 * 4 + 2][row] = v.z; xt[c4 * 4 + 3][row] = v.w;
        }
        __syncthreads();
#pragma unroll
        for (int j = 0; j < 32; ++j) {
            float xv = xt[kq * 32 + j][tl];
#pragma unroll
            for (int e = 0; e < NE; e++)
                acc[e] = fmaf(xv, wgl[e * D_IN + c * 256 + kq * 32 + j], acc[e]);
        }
    }
#pragma unroll
    for (int e = 0; e < NE; e++) part[tid * 9 + e] = acc[e];
    __syncthreads();

    int i1 = 0, i2 = -1, lp1 = 0, lp2 = 0;
    if (tid < 32) {
        float s8[NE];
#pragma unroll
        for (int e = 0; e < NE; e++) {
            float s = 0.f;
#pragma unroll
            for (int q = 0; q < 8; q++) s += part[(q * 32 + tid) * 9 + e];
            s8[e] = s;
        }
        float m = s8[0];
#pragma unroll
        for (int e = 1; e < NE; e++) m = fmaxf(m, s8[e]);
        float p[NE], s = 0.f;
#pragma unroll
        for (int e = 0; e < NE; e++) { p[e] = expf(s8[e] - m); s += p[e]; }
        float inv = 1.f / s;
        float v1 = p[0];
#pragma unroll
        for (int e = 1; e < NE; e++) if (p[e] > v1) { v1 = p[e]; i1 = e; }
        float v2 = -1.f;
#pragma unroll
        for (int e = 0; e < NE; e++) if (e != i1 && p[e] > v2) { v2 = p[e]; i2 = e; }
        int t = t0 + tid;
        wpair[2 * t]     = v1 * inv;
        wpair[2 * t + 1] = v2 * inv;
        lp1 = atomicAdd(&ecnt[i1], 1);
        lp2 = atomicAdd(&ecnt[i2], 1);
    }
    __syncthreads();
    if (tid < NE) gbase[tid] = atomicAdd(&cnt[tid], ecnt[tid]);
    __syncthreads();
    if (tid < 32) {
        int t = t0 + tid;
        bt[i1 * T_TOK + gbase[i1] + lp1] = (u16)(2 * t);
        bt[i2 * T_TOK + gbase[i2] + lp2] = (u16)(2 * t + 1);
    }
}

// -- 3. fc1 + GLU -> act_s: 64-row M-tiles, 2-phase loop --------------------
__global__ __launch_bounds__(256) void fc1_kernel(
    const u16* __restrict__ xb, const u16* __restrict__ f1s,
    const int* __restrict__ cnt, const u16* __restrict__ bt,
    u16* __restrict__ acts)
{
    __shared__ __align__(16) u16 asl[2][2048];
    __shared__ __align__(16) u16 bsl[2][4096];
    __shared__ u16 slot_l[64];

    const int bid = blockIdx.x;
    const int e   = bid & 7;
    const int nt  = (bid >> 3) & 3;
    const int mt  = bid >> 5;
    const int n   = cnt[e];
    const int row0 = mt * 64;
    if (row0 >= n) return;

    int tpre = 0;
#pragma unroll
    for (int ee = 0; ee < NE; ++ee)
        if (ee < e) tpre += (cnt[ee] + 127) >> 7;
    const int g = tpre + (mt >> 1);
    const int mhalf = mt & 1;

    const int tid = threadIdx.x;
    const int wv  = tid >> 6, lane = tid & 63;
    const int l15 = lane & 15, lhi = lane >> 4;
    const int wr  = wv >> 1, wc = wv & 1;

    if (tid < 64) {
        int r = row0 + tid;
        slot_l[tid] = bt[e * T_TOK + ((r < n) ? r : (n - 1))];
    }
    __syncthreads();

    const u16* srcA  = xb + (size_t)(slot_l[wv * 16 + l15] >> 1) * D_IN + lhi * 8;
    const int fb0 = wv * 2, fb1 = wv * 2 + 1;
    const u16* srcB0 = f1s + (size_t)(e * 4 + nt) * 65536 + fb0 * 512 + lane * 8;
    const u16* srcB1 = f1s + (size_t)(e * 4 + nt) * 65536 + fb1 * 512 + lane * 8;

#define ISS1(KS, BUF) {                                          \
    GLL16(srcA  + (KS) * 32,   &asl[BUF][wv * 512]);             \
    GLL16(srcB0 + (KS) * 4096, &bsl[BUF][fb0 * 512]);            \
    GLL16(srcB1 + (KS) * 4096, &bsl[BUF][fb1 * 512]); }

    f32x4 acc[2][4];
#pragma unroll
    for (int m = 0; m < 2; m++)
#pragma unroll
        for (int nb = 0; nb < 4; nb++) acc[m][nb] = (f32x4)0.f;

    ISS1(0, 0);
    __syncthreads();

#pragma unroll
    for (int ks = 0; ks < 16; ++ks) {
        const int cur = ks & 1;
        if (ks < 15) ISS1(ks + 1, cur ^ 1);
        bf16x8 a[2], b[4];
#pragma unroll
        for (int m = 0; m < 2; m++)
            a[m] = *(const bf16x8*)&asl[cur][(wr * 2 + m) * 512 + lane * 8];
        b[0] = *(const bf16x8*)&bsl[cur][(wc * 2 + 0) * 512 + lane * 8];
        b[1] = *(const bf16x8*)&bsl[cur][(wc * 2 + 1) * 512 + lane * 8];
        b[2] = *(const bf16x8*)&bsl[cur][(4 + wc * 2 + 0) * 512 + lane * 8];
        b[3] = *(const bf16x8*)&bsl[cur][(4 + wc * 2 + 1) * 512 + lane * 8];
#pragma unroll
        for (int m = 0; m < 2; m++)
#pragma unroll
            for (int nb = 0; nb < 4; nb++)
                acc[m][nb] = __builtin_amdgcn_mfma_f32_16x16x32_bf16(
                    a[m], b[nb], acc[m][nb], 0, 0, 0);
        __syncthreads();
    }

    u16* glu = &bsl[0][0];
#pragma unroll
    for (int m = 0; m < 2; m++) {
#pragma unroll
        for (int j = 0; j < 4; j++) {
            int row = wr * 32 + m * 16 + lhi * 4 + j;
#pragma unroll
            for (int q = 0; q < 2; q++) {
                float y = acc[m][q][j], gv = acc[m][q + 2][j];
                float v = y * gv / (1.f + __expf(-gv));
                glu[row * 72 + wc * 32 + q * 16 + l15] = f32_bf16(v);
            }
        }
    }
    __syncthreads();

    u16* tile = acts + (size_t)g * 32768;
#pragma unroll
    for (int i = 0; i < 2; ++i) {
        int c = wv * 2 + i;
        int mfl = c >> 1, ksr = c & 1;
        bf16x8 v = *(const bf16x8*)&glu[(mfl * 16 + l15) * 72 + ksr * 32 + lhi * 8];
        *(bf16x8*)&tile[(2 * nt + ksr) * 4096 + (mhalf * 4 + mfl) * 512 + lane * 8] = v;
    }
#undef ISS1
}

// -- 4. fc2 -> og: 64-row M-tiles, 2-phase loop -----------------------------
__global__ __launch_bounds__(256) void fc2_kernel(
    const u16* __restrict__ acts, const u16* __restrict__ f2s,
    const int* __restrict__ cnt, const u16* __restrict__ bt,
    u16* __restrict__ og)
{
    __shared__ __align__(16) u16 asl[2][2048];
    __shared__ __align__(16) u16 bsl[2][4096];
    __shared__ u16 slot_l[64];

    const int bid = blockIdx.x;
    const int e   = bid & 7;
    const int nt  = (bid >> 3) & 3;
    const int mt  = bid >> 5;
    const int n   = cnt[e];
    const int row0 = mt * 64;
    if (row0 >= n) return;

    int tpre = 0;
#pragma unroll
    for (int ee = 0; ee < NE; ++ee)
        if (ee < e) tpre += (cnt[ee] + 127) >> 7;
    const int g = tpre + (mt >> 1);
    const int mhalf = mt & 1;

    const int tid = threadIdx.x;
    const int wv  = tid >> 6, lane = tid & 63;
    const int l15 = lane & 15, lhi = lane >> 4;
    const int wr  = wv >> 1, wc = wv & 1;

    if (tid < 64) {
        int r = row0 + tid;
        slot_l[tid] = bt[e * T_TOK + ((r < n) ? r : (n - 1))];
    }
    __syncthreads();

    const int fb0 = wv * 2, fb1 = wv * 2 + 1;
    const u16* srcA  = acts + (size_t)g * 32768 + (mhalf * 4 + wv) * 512 + lane * 8;
    const u16* srcB0 = f2s + (size_t)(e * 4 + nt) * 32768 + fb0 * 512 + lane * 8;
    const u16* srcB1 = f2s + (size_t)(e * 4 + nt) * 32768 + fb1 * 512 + lane * 8;

#define ISS2(KS, BUF) {                                          \
    GLL16(srcA  + (KS) * 4096, &asl[BUF][wv * 512]);             \
    GLL16(srcB0 + (KS) * 4096, &bsl[BUF][fb0 * 512]);            \
    GLL16(srcB1 + (KS) * 4096, &bsl[BUF][fb1 * 512]); }

    f32x4 acc[2][4];
#pragma unroll
    for (int m = 0; m < 2; m++)
#pragma unroll
        for (int nb = 0; nb < 4; nb++) acc[m][nb] = (f32x4)0.f;

    ISS2(0, 0);
    __syncthreads();

#pragma unroll
    for (int ks = 0; ks < 8; ++ks) {
        const int cur = ks & 1;
        if (ks < 7) ISS2(ks + 1, cur ^ 1);
        bf16x8 a[2], b[4];
#pragma unroll
        for (int m = 0; m < 2; m++)
            a[m] = *(const bf16x8*)&asl[cur][(wr * 2 + m) * 512 + lane * 8];
#pragma unroll
        for (int nb = 0; nb < 4; nb++)
            b[nb] = *(const bf16x8*)&bsl[cur][(wc * 4 + nb) * 512 + lane * 8];
#pragma unroll
        for (int m = 0; m < 2; m++)
#pragma unroll
            for (int nb = 0; nb < 4; nb++)
                acc[m][nb] = __builtin_amdgcn_mfma_f32_16x16x32_bf16(
                    a[m], b[nb], acc[m][nb], 0, 0, 0);
        __syncthreads();
    }

#pragma unroll
    for (int m = 0; m < 2; m++) {
#pragma unroll
        for (int j = 0; j < 4; j++) {
            int lrow = wr * 32 + m * 16 + lhi * 4 + j;
            if (row0 + lrow < n) {
                int slot = slot_l[lrow];
                u16* dst = og + (size_t)slot * D_IN + nt * 128 + wc * 64 + l15;
#pragma unroll
                for (int nb = 0; nb < 4; nb++)
                    dst[nb * 16] = f32_bf16(acc[m][nb][j]);
            }
        }
    }
#undef ISS2
}

// ---------------- 5. combine ----------------
__global__ __launch_bounds__(256) void combine_kernel(
    const u16* __restrict__ og, const float* __restrict__ wpair,
    float* __restrict__ out)
{
    int idx = blockIdx.x * 256 + threadIdx.x;
    int t  = idx >> 6;
    int c8 = (idx & 63) * 8;
    float w0 = wpair[2 * t], w1 = wpair[2 * t + 1];
    bf16x8 a = *(const bf16x8*)&og[(size_t)(2 * t) * D_IN + c8];
    bf16x8 b = *(const bf16x8*)&og[(size_t)(2 * t + 1) * D_IN + c8];
    float4 o0, o1;
#pragma unroll
    for (int j = 0; j < 4; j++) {
        o0[j] = w0 * bf16_f32((u16)a[j])     + w1 * bf16_f32((u16)b[j]);
        o1[j] = w0 * bf16_f32((u16)a[j + 4]) + w1 * bf16_f32((u16)b[j + 4]);
    }
    float* orow = out + (size_t)t * D_IN + c8;
    *(float4*)orow = o0;
    *(float4*)(orow + 4) = o1;
}

// ---------------- launch ----------------
extern "C" void kernel_launch(void* const* d_in, const int* in_sizes, int n_in,
                              void* d_out, int out_size, void* d_ws, size_t ws_size,
                              hipStream_t stream) {
    const float* x   = (const float*)d_in[0];
    const float* wg  = (const float*)d_in[1];
    const float* fc1 = (const float*)d_in[2];
    const float* fc2 = (const float*)d_in[3];
    float* out = (float*)d_out;
    char* ws = (char*)d_ws;

    int*   cnt   = (int*)(ws + WS_CNT);
    float* wpair = (float*)(ws + WS_WP);
    u16*   bt    = (u16*)(ws + WS_BT);
    u16*   f2s   = (u16*)(ws + WS_F2B);
    u16*   f1s   = (u16*)(ws + WS_F1B);
    u16*   xb    = (u16*)(ws + WS_XB);
    u16*   acts  = (u16*)(ws + WS_AS);
    u16*   og    = (u16*)(ws + WS_OG);

    cvt_kernel<<<1024, 256, 0, stream>>>(fc1, fc2, f1s, f2s, cnt);
    gate_kernel<<<T_TOK / 32, 256, 0, stream>>>(x, wg, cnt, bt, wpair, xb);
    fc1_kernel<<<4096, 256, 0, stream>>>(xb, f1s, cnt, bt, acts);
    fc2_kernel<<<4096, 256, 0, stream>>>(acts, f2s, cnt, bt, og);
    combine_kernel<<<T_TOK * (D_IN / 8) / 256, 256, 0, stream>>>(og, wpair, out);
}